// Round 1
// baseline (1871.739 us; speedup 1.0000x reference)
//
#include <hip/hip_runtime.h>
#include <math.h>

#define B_ 4
#define S_ 2048
#define E_ 1024
#define H_ 16
#define D_ 64
#define M_ (B_ * S_)   // 8192

// ---------------------------------------------------------------------------
// GEMM: C[M,N] = A[M,K] @ W[K,N] + bias[N]   (fp32, VALU)
// 128x128 tile, BK=16, 256 threads, 8x8 micro-tile.
// A staged transposed in LDS -> both fragment reads are ds_read_b128.
// ---------------------------------------------------------------------------
__global__ __launch_bounds__(256)
void gemm_bias_kernel(const float* __restrict__ A, const float* __restrict__ Bm,
                      const float* __restrict__ bias, float* __restrict__ C,
                      int M, int N, int K)
{
    constexpr int BM = 128, BN = 128, BK = 16;
    __shared__ float AsT[BK][BM + 4];   // [k][m]
    __shared__ float Bs [BK][BN + 4];   // [k][n]

    const int tid = threadIdx.x;
    const int tx = tid & 15, ty = tid >> 4;
    const int r0 = ty * 8, c0 = tx * 8;
    const int m0 = blockIdx.x * BM, n0 = blockIdx.y * BN;

    // staging coords
    const int arow = tid >> 1;          // 0..127
    const int acol = (tid & 1) * 8;     // 0 or 8
    const int brow = tid >> 4;          // 0..15
    const int bcol = (tid & 15) * 4;    // 0..60

    float acc[8][8] = {};

    for (int k0 = 0; k0 < K; k0 += BK) {
        // ---- stage A tile (transposed) ----
        const float* ap = A + (size_t)(m0 + arow) * K + k0 + acol;
        float4 a0 = *(const float4*)ap;
        float4 a1 = *(const float4*)(ap + 4);
        AsT[acol + 0][arow] = a0.x;
        AsT[acol + 1][arow] = a0.y;
        AsT[acol + 2][arow] = a0.z;
        AsT[acol + 3][arow] = a0.w;
        AsT[acol + 4][arow] = a1.x;
        AsT[acol + 5][arow] = a1.y;
        AsT[acol + 6][arow] = a1.z;
        AsT[acol + 7][arow] = a1.w;
        // ---- stage B tile ----
        const float* bp = Bm + (size_t)(k0 + brow) * N + n0 + bcol;
        *(float4*)&Bs[brow][bcol]      = *(const float4*)bp;
        *(float4*)&Bs[brow][bcol + 64] = *(const float4*)(bp + 64);
        __syncthreads();

        #pragma unroll
        for (int k = 0; k < BK; ++k) {
            float4 fa0 = *(const float4*)&AsT[k][r0];
            float4 fa1 = *(const float4*)&AsT[k][r0 + 4];
            float4 fb0 = *(const float4*)&Bs[k][c0];
            float4 fb1 = *(const float4*)&Bs[k][c0 + 4];
            float av[8] = {fa0.x, fa0.y, fa0.z, fa0.w, fa1.x, fa1.y, fa1.z, fa1.w};
            float bv[8] = {fb0.x, fb0.y, fb0.z, fb0.w, fb1.x, fb1.y, fb1.z, fb1.w};
            #pragma unroll
            for (int i = 0; i < 8; ++i)
                #pragma unroll
                for (int j = 0; j < 8; ++j)
                    acc[i][j] = fmaf(av[i], bv[j], acc[i][j]);
        }
        __syncthreads();
    }

    // epilogue: += bias, store
    float4 bsa = *(const float4*)&bias[n0 + c0];
    float4 bsb = *(const float4*)&bias[n0 + c0 + 4];
    #pragma unroll
    for (int i = 0; i < 8; ++i) {
        float* cp = C + (size_t)(m0 + r0 + i) * N + n0 + c0;
        float4 o0 = make_float4(acc[i][0] + bsa.x, acc[i][1] + bsa.y,
                                acc[i][2] + bsa.z, acc[i][3] + bsa.w);
        float4 o1 = make_float4(acc[i][4] + bsb.x, acc[i][5] + bsb.y,
                                acc[i][6] + bsb.z, acc[i][7] + bsb.w);
        *(float4*)cp       = o0;
        *(float4*)(cp + 4) = o1;
    }
}

// ---------------------------------------------------------------------------
// Flash attention (fp32, unmasked). One block = (b, h, 64-query tile).
// 256 threads as 16x16: thread owns 4 query rows x 4 cols.
// LDS: Qs (scaled), KP (K^T, then reused for P), Vs.  52 KB total.
// ---------------------------------------------------------------------------
__global__ __launch_bounds__(256)
void attn_kernel(const float* __restrict__ qkv, float* __restrict__ out)
{
    __shared__ float Qs[64][68];   // [q][d], pre-scaled by 1/sqrt(D)
    __shared__ float KP[64][68];   // phase 1: K^T [d][key]; phase 2: P [q][key]
    __shared__ float Vs[64][68];   // [key][d]

    const int tid = threadIdx.x;
    const int tx = tid & 15, ty = tid >> 4;
    const int qb = blockIdx.x, h = blockIdx.y, b = blockIdx.z;

    const int q0 = ty * 4;         // local query rows owned
    const int c0 = tx * 4;         // local cols owned (key idx or d idx)

    // ---- stage Q once, scaled ----
    {
        int r  = tid >> 2;            // 0..63
        int d0 = (tid & 3) * 16;      // 0,16,32,48
        const float* qp = qkv + ((size_t)(b * S_ + qb * 64 + r)) * (3 * E_) + h * 64 + d0;
        #pragma unroll
        for (int w = 0; w < 4; ++w) {
            float4 v = *(const float4*)(qp + w * 4);
            float4 sv = make_float4(v.x * 0.125f, v.y * 0.125f, v.z * 0.125f, v.w * 0.125f);
            *(float4*)&Qs[r][d0 + w * 4] = sv;
        }
    }

    float m_run[4] = {-INFINITY, -INFINITY, -INFINITY, -INFINITY};
    float l_run[4] = {0.f, 0.f, 0.f, 0.f};
    float o[4][4] = {};

    for (int kb = 0; kb < S_; kb += 64) {
        __syncthreads();   // prior iteration done reading KP/Vs
        // ---- stage K^T and V ----
        {
            int key = tid >> 2;
            int d0  = (tid & 3) * 16;
            const float* kp = qkv + ((size_t)(b * S_ + kb + key)) * (3 * E_) + E_ + h * 64 + d0;
            const float* vp = kp + E_;
            #pragma unroll
            for (int w = 0; w < 4; ++w) {
                float4 kv = *(const float4*)(kp + w * 4);
                KP[d0 + w * 4 + 0][key] = kv.x;
                KP[d0 + w * 4 + 1][key] = kv.y;
                KP[d0 + w * 4 + 2][key] = kv.z;
                KP[d0 + w * 4 + 3][key] = kv.w;
                *(float4*)&Vs[key][d0 + w * 4] = *(const float4*)(vp + w * 4);
            }
        }
        __syncthreads();

        // ---- scores: s[i][j] = Qs[q0+i][:] . K[c0+j][:]  (Q pre-scaled) ----
        float sc[4][4] = {};
        #pragma unroll 8
        for (int d = 0; d < 64; ++d) {
            float4 kv = *(const float4*)&KP[d][c0];
            float qv[4] = {Qs[q0 + 0][d], Qs[q0 + 1][d], Qs[q0 + 2][d], Qs[q0 + 3][d]};
            #pragma unroll
            for (int i = 0; i < 4; ++i) {
                sc[i][0] = fmaf(qv[i], kv.x, sc[i][0]);
                sc[i][1] = fmaf(qv[i], kv.y, sc[i][1]);
                sc[i][2] = fmaf(qv[i], kv.z, sc[i][2]);
                sc[i][3] = fmaf(qv[i], kv.w, sc[i][3]);
            }
        }

        // ---- online softmax ----
        #pragma unroll
        for (int i = 0; i < 4; ++i) {
            float v = fmaxf(fmaxf(sc[i][0], sc[i][1]), fmaxf(sc[i][2], sc[i][3]));
            v = fmaxf(v, __shfl_xor(v, 1));
            v = fmaxf(v, __shfl_xor(v, 2));
            v = fmaxf(v, __shfl_xor(v, 4));
            v = fmaxf(v, __shfl_xor(v, 8));
            float mn = fmaxf(m_run[i], v);
            float alpha = __expf(m_run[i] - mn);
            m_run[i] = mn;
            #pragma unroll
            for (int j = 0; j < 4; ++j) sc[i][j] = __expf(sc[i][j] - mn);
            float rs = (sc[i][0] + sc[i][1]) + (sc[i][2] + sc[i][3]);
            rs += __shfl_xor(rs, 1);
            rs += __shfl_xor(rs, 2);
            rs += __shfl_xor(rs, 4);
            rs += __shfl_xor(rs, 8);
            l_run[i] = l_run[i] * alpha + rs;
            #pragma unroll
            for (int j = 0; j < 4; ++j) o[i][j] *= alpha;
        }

        __syncthreads();   // all K^T reads done; reuse KP for P
        #pragma unroll
        for (int i = 0; i < 4; ++i)
            *(float4*)&KP[q0 + i][c0] = make_float4(sc[i][0], sc[i][1], sc[i][2], sc[i][3]);
        __syncthreads();

        // ---- O += P @ V ----
        #pragma unroll 8
        for (int kk = 0; kk < 64; ++kk) {
            float4 vv = *(const float4*)&Vs[kk][c0];
            float pv[4] = {KP[q0 + 0][kk], KP[q0 + 1][kk], KP[q0 + 2][kk], KP[q0 + 3][kk]};
            #pragma unroll
            for (int i = 0; i < 4; ++i) {
                o[i][0] = fmaf(pv[i], vv.x, o[i][0]);
                o[i][1] = fmaf(pv[i], vv.y, o[i][1]);
                o[i][2] = fmaf(pv[i], vv.z, o[i][2]);
                o[i][3] = fmaf(pv[i], vv.w, o[i][3]);
            }
        }
    }

    // ---- epilogue: normalize, write [B,S,H*D] ----
    #pragma unroll
    for (int i = 0; i < 4; ++i) {
        float inv = 1.0f / l_run[i];
        int sq = qb * 64 + q0 + i;
        float* op = out + ((size_t)(b * S_ + sq)) * E_ + h * 64 + c0;
        *(float4*)op = make_float4(o[i][0] * inv, o[i][1] * inv, o[i][2] * inv, o[i][3] * inv);
    }
}

// ---------------------------------------------------------------------------
extern "C" void kernel_launch(void* const* d_in, const int* in_sizes, int n_in,
                              void* d_out, int out_size, void* d_ws, size_t ws_size,
                              hipStream_t stream)
{
    const float* x     = (const float*)d_in[0];   // [B,S,E]
    const float* w_in  = (const float*)d_in[1];   // [E,3E]
    const float* b_in  = (const float*)d_in[2];   // [3E]
    const float* w_out = (const float*)d_in[3];   // [E,E]
    const float* b_out = (const float*)d_in[4];   // [E]
    float* outp = (float*)d_out;

    float* qkv  = (float*)d_ws;                         // [B,S,3E]  100.7 MB
    float* attn = qkv + (size_t)B_ * S_ * 3 * E_;       // [B,S,E]    33.6 MB

    // 1) qkv = x @ w_in + b_in
    gemm_bias_kernel<<<dim3(M_ / 128, (3 * E_) / 128), 256, 0, stream>>>(
        x, w_in, b_in, qkv, M_, 3 * E_, E_);

    // 2) attention
    attn_kernel<<<dim3(S_ / 64, H_, B_), 256, 0, stream>>>(qkv, attn);

    // 3) out = attn @ w_out + b_out
    gemm_bias_kernel<<<dim3(M_ / 128, E_ / 128), 256, 0, stream>>>(
        attn, w_out, b_out, outp, M_, E_, E_);
}

// Round 2
// 1365.846 us; speedup vs baseline: 1.3704x; 1.3704x over previous
//
#include <hip/hip_runtime.h>
#include <math.h>

#define B_ 4
#define S_ 2048
#define E_ 1024
#define H_ 16
#define D_ 64
#define M_ (B_ * S_)   // 8192

using f32x4  = __attribute__((ext_vector_type(4))) float;
using short8 = __attribute__((ext_vector_type(8))) short;
using ushort8_t = __attribute__((ext_vector_type(8))) unsigned short;

// split f into hi (bf16 truncation) + lo (bf16 RNE of residual); hi+lo ~= f to 2^-17
__device__ inline void splitf(float f, unsigned short& h, unsigned short& l) {
    unsigned u = __float_as_uint(f);
    h = (unsigned short)(u >> 16);
    float hf = __uint_as_float(u & 0xffff0000u);
    float lf = f - hf;                      // exact
    unsigned v = __float_as_uint(lf);
    l = (unsigned short)((v + 0x7fffu + ((v >> 16) & 1u)) >> 16);   // RNE
}
__device__ inline float b2f(unsigned short s) {
    return __uint_as_float(((unsigned)s) << 16);
}

// ---------------------------------------------------------------------------
// transpose + split: W[R][C] fp32  ->  Th/Tl[C][R] bf16
// ---------------------------------------------------------------------------
__global__ __launch_bounds__(256)
void transpose_split_kernel(const float* __restrict__ W,
                            unsigned short* __restrict__ Th,
                            unsigned short* __restrict__ Tl, int R, int C)
{
    __shared__ float t[32][33];
    const int tx = threadIdx.x & 31, ty = threadIdx.x >> 5;   // ty 0..7
    const int c0 = blockIdx.x * 32, r0 = blockIdx.y * 32;
    #pragma unroll
    for (int i = 0; i < 4; ++i)
        t[ty + 8 * i][tx] = W[(size_t)(r0 + ty + 8 * i) * C + c0 + tx];
    __syncthreads();
    #pragma unroll
    for (int i = 0; i < 4; ++i) {
        float v = t[tx][ty + 8 * i];
        unsigned short h, l;
        splitf(v, h, l);
        size_t idx = (size_t)(c0 + ty + 8 * i) * R + r0 + tx;
        Th[idx] = h;
        Tl[idx] = l;
    }
}

// ---------------------------------------------------------------------------
// Split-bf16 MFMA GEMM: C[M,N] = A[M,K] @ B[K,N] + bias
//   A: fp32 (split on the fly) or pre-split bf16 hi/lo  [M][K]
//   B: pre-split transposed bf16 hi/lo  Bt[N][K]
//   C: fp32 or split bf16 hi/lo
// 128x128 tile, BK=32, 4 waves (2x2 of 64x64), 16x16x32 MFMA, 3 mfma/product.
// ---------------------------------------------------------------------------
template<bool A_SPLIT_IN, bool OUT_SPLIT>
__global__ __launch_bounds__(256)
void gemm_mfma_kernel(const float* __restrict__ Af,
                      const unsigned short* __restrict__ Ah,
                      const unsigned short* __restrict__ Al,
                      const unsigned short* __restrict__ Bth,
                      const unsigned short* __restrict__ Btl,
                      const float* __restrict__ bias,
                      float* __restrict__ Cf,
                      unsigned short* __restrict__ Ch,
                      unsigned short* __restrict__ Cl,
                      int M, int N, int K)
{
    constexpr int LDK = 40;   // 32 + 8 pad (bf16 units): row stride 20 dwords -> 2-way max
    __shared__ unsigned short AsH[128][LDK];
    __shared__ unsigned short AsL[128][LDK];
    __shared__ unsigned short BsH[128][LDK];
    __shared__ unsigned short BsL[128][LDK];

    const int tid  = threadIdx.x;
    const int lane = tid & 63;
    const int wave = tid >> 6;
    const int wm = (wave >> 1) * 64, wn = (wave & 1) * 64;
    const int ln = lane & 15, qd = lane >> 4;
    const int m0 = blockIdx.x * 128, n0 = blockIdx.y * 128;

    f32x4 acc[4][4] = {};

    for (int k0 = 0; k0 < K; k0 += 32) {
        // ---- stage A ----
        if (!A_SPLIT_IN) {
            #pragma unroll
            for (int i = 0; i < 4; ++i) {
                int g = tid + 256 * i;
                int row = g >> 3, kc = (g & 7) * 4;
                float4 v = *(const float4*)(Af + (size_t)(m0 + row) * K + k0 + kc);
                ushort4 hv, lv;
                splitf(v.x, hv.x, lv.x);
                splitf(v.y, hv.y, lv.y);
                splitf(v.z, hv.z, lv.z);
                splitf(v.w, hv.w, lv.w);
                *(ushort4*)&AsH[row][kc] = hv;
                *(ushort4*)&AsL[row][kc] = lv;
            }
        } else {
            #pragma unroll
            for (int i = 0; i < 2; ++i) {
                int g = tid + 256 * i;
                int row = g >> 2, kc = (g & 3) * 8;
                *(ushort8_t*)&AsH[row][kc] =
                    *(const ushort8_t*)(Ah + (size_t)(m0 + row) * K + k0 + kc);
                *(ushort8_t*)&AsL[row][kc] =
                    *(const ushort8_t*)(Al + (size_t)(m0 + row) * K + k0 + kc);
            }
        }
        // ---- stage Bt (pre-split, k-major) ----
        #pragma unroll
        for (int i = 0; i < 2; ++i) {
            int g = tid + 256 * i;
            int row = g >> 2, kc = (g & 3) * 8;
            *(ushort8_t*)&BsH[row][kc] =
                *(const ushort8_t*)(Bth + (size_t)(n0 + row) * K + k0 + kc);
            *(ushort8_t*)&BsL[row][kc] =
                *(const ushort8_t*)(Btl + (size_t)(n0 + row) * K + k0 + kc);
        }
        __syncthreads();

        short8 ah[4], al[4], bh[4], bl[4];
        #pragma unroll
        for (int mt = 0; mt < 4; ++mt) {
            ah[mt] = *(const short8*)&AsH[wm + mt * 16 + ln][qd * 8];
            al[mt] = *(const short8*)&AsL[wm + mt * 16 + ln][qd * 8];
        }
        #pragma unroll
        for (int nt = 0; nt < 4; ++nt) {
            bh[nt] = *(const short8*)&BsH[wn + nt * 16 + ln][qd * 8];
            bl[nt] = *(const short8*)&BsL[wn + nt * 16 + ln][qd * 8];
        }
        #pragma unroll
        for (int mt = 0; mt < 4; ++mt)
            #pragma unroll
            for (int nt = 0; nt < 4; ++nt) {
                acc[mt][nt] = __builtin_amdgcn_mfma_f32_16x16x32_bf16(
                    ah[mt], bh[nt], acc[mt][nt], 0, 0, 0);
                acc[mt][nt] = __builtin_amdgcn_mfma_f32_16x16x32_bf16(
                    ah[mt], bl[nt], acc[mt][nt], 0, 0, 0);
                acc[mt][nt] = __builtin_amdgcn_mfma_f32_16x16x32_bf16(
                    al[mt], bh[nt], acc[mt][nt], 0, 0, 0);
            }
        __syncthreads();
    }

    // ---- epilogue ----
    #pragma unroll
    for (int nt = 0; nt < 4; ++nt) {
        const int col = n0 + wn + nt * 16 + ln;
        const float bv = bias[col];
        #pragma unroll
        for (int mt = 0; mt < 4; ++mt) {
            #pragma unroll
            for (int r = 0; r < 4; ++r) {
                const int row = m0 + wm + mt * 16 + qd * 4 + r;
                float f = acc[mt][nt][r] + bv;
                size_t idx = (size_t)row * N + col;
                if (OUT_SPLIT) {
                    unsigned short h, l;
                    splitf(f, h, l);
                    Ch[idx] = h;
                    Cl[idx] = l;
                } else {
                    Cf[idx] = f;
                }
            }
        }
    }
}

// ---------------------------------------------------------------------------
// Flash attention (fp32 math, unmasked). Reads split-bf16 qkv, writes split
// bf16 attn output. One block = (b, h, 64-query tile); 256 threads as 16x16.
// ---------------------------------------------------------------------------
__global__ __launch_bounds__(256)
void attn_kernel(const unsigned short* __restrict__ qkvh,
                 const unsigned short* __restrict__ qkvl,
                 unsigned short* __restrict__ outh,
                 unsigned short* __restrict__ outl)
{
    __shared__ float Qs[64][68];   // [q][d], pre-scaled by 1/sqrt(D)
    __shared__ float KP[64][68];   // phase 1: K^T [d][key]; phase 2: P [q][key]
    __shared__ float Vs[64][68];   // [key][d]

    const int tid = threadIdx.x;
    const int tx = tid & 15, ty = tid >> 4;
    const int qb = blockIdx.x, h = blockIdx.y, b = blockIdx.z;

    const int q0 = ty * 4;
    const int c0 = tx * 4;

    // ---- stage Q once, scaled ----
    {
        int r  = tid >> 2;
        int d0 = (tid & 3) * 16;
        size_t base = ((size_t)(b * S_ + qb * 64 + r)) * (3 * E_) + h * 64 + d0;
        #pragma unroll
        for (int w = 0; w < 4; ++w) {
            ushort4 hv = *(const ushort4*)(qkvh + base + w * 4);
            ushort4 lv = *(const ushort4*)(qkvl + base + w * 4);
            float4 sv = make_float4((b2f(hv.x) + b2f(lv.x)) * 0.125f,
                                    (b2f(hv.y) + b2f(lv.y)) * 0.125f,
                                    (b2f(hv.z) + b2f(lv.z)) * 0.125f,
                                    (b2f(hv.w) + b2f(lv.w)) * 0.125f);
            *(float4*)&Qs[r][d0 + w * 4] = sv;
        }
    }

    float m_run[4] = {-INFINITY, -INFINITY, -INFINITY, -INFINITY};
    float l_run[4] = {0.f, 0.f, 0.f, 0.f};
    float o[4][4] = {};

    for (int kb = 0; kb < S_; kb += 64) {
        __syncthreads();
        {
            int key = tid >> 2;
            int d0  = (tid & 3) * 16;
            size_t kbase = ((size_t)(b * S_ + kb + key)) * (3 * E_) + E_ + h * 64 + d0;
            size_t vbase = kbase + E_;
            #pragma unroll
            for (int w = 0; w < 4; ++w) {
                ushort4 khv = *(const ushort4*)(qkvh + kbase + w * 4);
                ushort4 klv = *(const ushort4*)(qkvl + kbase + w * 4);
                KP[d0 + w * 4 + 0][key] = b2f(khv.x) + b2f(klv.x);
                KP[d0 + w * 4 + 1][key] = b2f(khv.y) + b2f(klv.y);
                KP[d0 + w * 4 + 2][key] = b2f(khv.z) + b2f(klv.z);
                KP[d0 + w * 4 + 3][key] = b2f(khv.w) + b2f(klv.w);
                ushort4 vhv = *(const ushort4*)(qkvh + vbase + w * 4);
                ushort4 vlv = *(const ushort4*)(qkvl + vbase + w * 4);
                *(float4*)&Vs[key][d0 + w * 4] =
                    make_float4(b2f(vhv.x) + b2f(vlv.x), b2f(vhv.y) + b2f(vlv.y),
                                b2f(vhv.z) + b2f(vlv.z), b2f(vhv.w) + b2f(vlv.w));
            }
        }
        __syncthreads();

        float sc[4][4] = {};
        #pragma unroll 8
        for (int d = 0; d < 64; ++d) {
            float4 kv = *(const float4*)&KP[d][c0];
            float qv[4] = {Qs[q0 + 0][d], Qs[q0 + 1][d], Qs[q0 + 2][d], Qs[q0 + 3][d]};
            #pragma unroll
            for (int i = 0; i < 4; ++i) {
                sc[i][0] = fmaf(qv[i], kv.x, sc[i][0]);
                sc[i][1] = fmaf(qv[i], kv.y, sc[i][1]);
                sc[i][2] = fmaf(qv[i], kv.z, sc[i][2]);
                sc[i][3] = fmaf(qv[i], kv.w, sc[i][3]);
            }
        }

        #pragma unroll
        for (int i = 0; i < 4; ++i) {
            float v = fmaxf(fmaxf(sc[i][0], sc[i][1]), fmaxf(sc[i][2], sc[i][3]));
            v = fmaxf(v, __shfl_xor(v, 1));
            v = fmaxf(v, __shfl_xor(v, 2));
            v = fmaxf(v, __shfl_xor(v, 4));
            v = fmaxf(v, __shfl_xor(v, 8));
            float mn = fmaxf(m_run[i], v);
            float alpha = __expf(m_run[i] - mn);
            m_run[i] = mn;
            #pragma unroll
            for (int j = 0; j < 4; ++j) sc[i][j] = __expf(sc[i][j] - mn);
            float rs = (sc[i][0] + sc[i][1]) + (sc[i][2] + sc[i][3]);
            rs += __shfl_xor(rs, 1);
            rs += __shfl_xor(rs, 2);
            rs += __shfl_xor(rs, 4);
            rs += __shfl_xor(rs, 8);
            l_run[i] = l_run[i] * alpha + rs;
            #pragma unroll
            for (int j = 0; j < 4; ++j) o[i][j] *= alpha;
        }

        __syncthreads();
        #pragma unroll
        for (int i = 0; i < 4; ++i)
            *(float4*)&KP[q0 + i][c0] = make_float4(sc[i][0], sc[i][1], sc[i][2], sc[i][3]);
        __syncthreads();

        #pragma unroll 8
        for (int kk = 0; kk < 64; ++kk) {
            float4 vv = *(const float4*)&Vs[kk][c0];
            float pv[4] = {KP[q0 + 0][kk], KP[q0 + 1][kk], KP[q0 + 2][kk], KP[q0 + 3][kk]};
            #pragma unroll
            for (int i = 0; i < 4; ++i) {
                o[i][0] = fmaf(pv[i], vv.x, o[i][0]);
                o[i][1] = fmaf(pv[i], vv.y, o[i][1]);
                o[i][2] = fmaf(pv[i], vv.z, o[i][2]);
                o[i][3] = fmaf(pv[i], vv.w, o[i][3]);
            }
        }
    }

    #pragma unroll
    for (int i = 0; i < 4; ++i) {
        float inv = 1.0f / l_run[i];
        int sq = qb * 64 + q0 + i;
        size_t base = ((size_t)(b * S_ + sq)) * E_ + h * 64 + c0;
        #pragma unroll
        for (int j = 0; j < 4; ++j) {
            unsigned short hh, ll;
            splitf(o[i][j] * inv, hh, ll);
            outh[base + j] = hh;
            outl[base + j] = ll;
        }
    }
}

// ---------------------------------------------------------------------------
extern "C" void kernel_launch(void* const* d_in, const int* in_sizes, int n_in,
                              void* d_out, int out_size, void* d_ws, size_t ws_size,
                              hipStream_t stream)
{
    const float* x     = (const float*)d_in[0];   // [B,S,E]
    const float* w_in  = (const float*)d_in[1];   // [E,3E]
    const float* b_in  = (const float*)d_in[2];   // [3E]
    const float* w_out = (const float*)d_in[3];   // [E,E]
    const float* b_out = (const float*)d_in[4];   // [E]
    float* outp = (float*)d_out;

    char* ws = (char*)d_ws;
    // persistent regions (total 134.2 MB, same footprint as round 1):
    unsigned short* qkvh = (unsigned short*)ws;                               // 50.33 MB
    unsigned short* qkvl = qkvh + (size_t)M_ * 3 * E_;                        // 50.33 MB
    unsigned short* attnh = qkvl + (size_t)M_ * 3 * E_;                       // 16.78 MB
    unsigned short* attnl = attnh + (size_t)M_ * E_;                          // 16.78 MB
    // transient: wInT parked in the (not yet written) attn region
    unsigned short* wInTh = attnh;                                            // [3E][E]
    unsigned short* wInTl = wInTh + (size_t)3 * E_ * E_;
    // transient: wOutT parked in the (dead after attention) qkv region
    unsigned short* wOutTh = qkvh;                                            // [E][E]
    unsigned short* wOutTl = wOutTh + (size_t)E_ * E_;

    // 1) wInT = transpose+split(w_in)   [E,3E] -> [3E,E]
    transpose_split_kernel<<<dim3(3 * E_ / 32, E_ / 32), 256, 0, stream>>>(
        w_in, wInTh, wInTl, E_, 3 * E_);

    // 2) qkv = x @ w_in + b_in  (split-bf16 MFMA, split output)
    gemm_mfma_kernel<false, true><<<dim3(M_ / 128, (3 * E_) / 128), 256, 0, stream>>>(
        x, nullptr, nullptr, wInTh, wInTl, b_in, nullptr, qkvh, qkvl,
        M_, 3 * E_, E_);

    // 3) attention (fp32 math), writes split attn
    attn_kernel<<<dim3(S_ / 64, H_, B_), 256, 0, stream>>>(qkvh, qkvl, attnh, attnl);

    // 4) wOutT = transpose+split(w_out) into dead qkv region
    transpose_split_kernel<<<dim3(E_ / 32, E_ / 32), 256, 0, stream>>>(
        w_out, wOutTh, wOutTl, E_, E_);

    // 5) out = attn @ w_out + b_out  (pre-split A, fp32 output)
    gemm_mfma_kernel<true, false><<<dim3(M_ / 128, E_ / 128), 256, 0, stream>>>(
        nullptr, attnh, attnl, wOutTh, wOutTl, b_out, outp, nullptr, nullptr,
        M_, E_, E_);
}

// Round 3
// 785.873 us; speedup vs baseline: 2.3817x; 1.7380x over previous
//
#include <hip/hip_runtime.h>
#include <math.h>

#define B_ 4
#define S_ 2048
#define E_ 1024
#define H_ 16
#define D_ 64
#define M_ (B_ * S_)   // 8192

using f32x4  = __attribute__((ext_vector_type(4))) float;
using short8 = __attribute__((ext_vector_type(8))) short;
using ushort8_t = __attribute__((ext_vector_type(8))) unsigned short;

// split f into hi (bf16 truncation) + lo (bf16 RNE of residual); hi+lo ~= f to 2^-17
__device__ inline void splitf(float f, unsigned short& h, unsigned short& l) {
    unsigned u = __float_as_uint(f);
    h = (unsigned short)(u >> 16);
    float hf = __uint_as_float(u & 0xffff0000u);
    float lf = f - hf;                      // exact
    unsigned v = __float_as_uint(lf);
    l = (unsigned short)((v + 0x7fffu + ((v >> 16) & 1u)) >> 16);   // RNE
}
__device__ inline unsigned short f2b(float f) {   // fp32 -> bf16 RNE
    unsigned v = __float_as_uint(f);
    return (unsigned short)((v + 0x7fffu + ((v >> 16) & 1u)) >> 16);
}

// ---------------------------------------------------------------------------
// transpose + split: W[R][C] fp32  ->  Th/Tl[C][R] bf16
// ---------------------------------------------------------------------------
__global__ __launch_bounds__(256)
void transpose_split_kernel(const float* __restrict__ W,
                            unsigned short* __restrict__ Th,
                            unsigned short* __restrict__ Tl, int R, int C)
{
    __shared__ float t[32][33];
    const int tx = threadIdx.x & 31, ty = threadIdx.x >> 5;   // ty 0..7
    const int c0 = blockIdx.x * 32, r0 = blockIdx.y * 32;
    #pragma unroll
    for (int i = 0; i < 4; ++i)
        t[ty + 8 * i][tx] = W[(size_t)(r0 + ty + 8 * i) * C + c0 + tx];
    __syncthreads();
    #pragma unroll
    for (int i = 0; i < 4; ++i) {
        float v = t[tx][ty + 8 * i];
        unsigned short h, l;
        splitf(v, h, l);
        size_t idx = (size_t)(c0 + ty + 8 * i) * R + r0 + tx;
        Th[idx] = h;
        Tl[idx] = l;
    }
}

// ---------------------------------------------------------------------------
// Split-bf16 MFMA GEMM: C[M,N] = A[M,K] @ B[K,N] + bias  (unchanged from R2)
// ---------------------------------------------------------------------------
template<bool A_SPLIT_IN, bool OUT_SPLIT>
__global__ __launch_bounds__(256)
void gemm_mfma_kernel(const float* __restrict__ Af,
                      const unsigned short* __restrict__ Ah,
                      const unsigned short* __restrict__ Al,
                      const unsigned short* __restrict__ Bth,
                      const unsigned short* __restrict__ Btl,
                      const float* __restrict__ bias,
                      float* __restrict__ Cf,
                      unsigned short* __restrict__ Ch,
                      unsigned short* __restrict__ Cl,
                      int M, int N, int K)
{
    constexpr int LDK = 40;
    __shared__ unsigned short AsH[128][LDK];
    __shared__ unsigned short AsL[128][LDK];
    __shared__ unsigned short BsH[128][LDK];
    __shared__ unsigned short BsL[128][LDK];

    const int tid  = threadIdx.x;
    const int lane = tid & 63;
    const int wave = tid >> 6;
    const int wm = (wave >> 1) * 64, wn = (wave & 1) * 64;
    const int ln = lane & 15, qd = lane >> 4;
    const int m0 = blockIdx.x * 128, n0 = blockIdx.y * 128;

    f32x4 acc[4][4] = {};

    for (int k0 = 0; k0 < K; k0 += 32) {
        if (!A_SPLIT_IN) {
            #pragma unroll
            for (int i = 0; i < 4; ++i) {
                int g = tid + 256 * i;
                int row = g >> 3, kc = (g & 7) * 4;
                float4 v = *(const float4*)(Af + (size_t)(m0 + row) * K + k0 + kc);
                ushort4 hv, lv;
                splitf(v.x, hv.x, lv.x);
                splitf(v.y, hv.y, lv.y);
                splitf(v.z, hv.z, lv.z);
                splitf(v.w, hv.w, lv.w);
                *(ushort4*)&AsH[row][kc] = hv;
                *(ushort4*)&AsL[row][kc] = lv;
            }
        } else {
            #pragma unroll
            for (int i = 0; i < 2; ++i) {
                int g = tid + 256 * i;
                int row = g >> 2, kc = (g & 3) * 8;
                *(ushort8_t*)&AsH[row][kc] =
                    *(const ushort8_t*)(Ah + (size_t)(m0 + row) * K + k0 + kc);
                *(ushort8_t*)&AsL[row][kc] =
                    *(const ushort8_t*)(Al + (size_t)(m0 + row) * K + k0 + kc);
            }
        }
        #pragma unroll
        for (int i = 0; i < 2; ++i) {
            int g = tid + 256 * i;
            int row = g >> 2, kc = (g & 3) * 8;
            *(ushort8_t*)&BsH[row][kc] =
                *(const ushort8_t*)(Bth + (size_t)(n0 + row) * K + k0 + kc);
            *(ushort8_t*)&BsL[row][kc] =
                *(const ushort8_t*)(Btl + (size_t)(n0 + row) * K + k0 + kc);
        }
        __syncthreads();

        short8 ah[4], al[4], bh[4], bl[4];
        #pragma unroll
        for (int mt = 0; mt < 4; ++mt) {
            ah[mt] = *(const short8*)&AsH[wm + mt * 16 + ln][qd * 8];
            al[mt] = *(const short8*)&AsL[wm + mt * 16 + ln][qd * 8];
        }
        #pragma unroll
        for (int nt = 0; nt < 4; ++nt) {
            bh[nt] = *(const short8*)&BsH[wn + nt * 16 + ln][qd * 8];
            bl[nt] = *(const short8*)&BsL[wn + nt * 16 + ln][qd * 8];
        }
        #pragma unroll
        for (int mt = 0; mt < 4; ++mt)
            #pragma unroll
            for (int nt = 0; nt < 4; ++nt) {
                acc[mt][nt] = __builtin_amdgcn_mfma_f32_16x16x32_bf16(
                    ah[mt], bh[nt], acc[mt][nt], 0, 0, 0);
                acc[mt][nt] = __builtin_amdgcn_mfma_f32_16x16x32_bf16(
                    ah[mt], bl[nt], acc[mt][nt], 0, 0, 0);
                acc[mt][nt] = __builtin_amdgcn_mfma_f32_16x16x32_bf16(
                    al[mt], bh[nt], acc[mt][nt], 0, 0, 0);
            }
        __syncthreads();
    }

    #pragma unroll
    for (int nt = 0; nt < 4; ++nt) {
        const int col = n0 + wn + nt * 16 + ln;
        const float bv = bias[col];
        #pragma unroll
        for (int mt = 0; mt < 4; ++mt) {
            #pragma unroll
            for (int r = 0; r < 4; ++r) {
                const int row = m0 + wm + mt * 16 + qd * 4 + r;
                float f = acc[mt][nt][r] + bv;
                size_t idx = (size_t)row * N + col;
                if (OUT_SPLIT) {
                    unsigned short h, l;
                    splitf(f, h, l);
                    Ch[idx] = h;
                    Cl[idx] = l;
                } else {
                    Cf[idx] = f;
                }
            }
        }
    }
}

// ---------------------------------------------------------------------------
// MFMA flash attention. Block = (b, h, 128-q tile); 4 waves x 32 q-rows.
// QK^T: split Q x split K (3 mfma). PV: bf16 P x split V (2 mfma).
// K staged [key][d] (B-operand layout); V staged transposed [d][key];
// P round-trips through LDS (C-layout -> A-operand layout).
// ---------------------------------------------------------------------------
__global__ __launch_bounds__(256)
void attn_mfma_kernel(const unsigned short* __restrict__ qkvh,
                      const unsigned short* __restrict__ qkvl,
                      unsigned short* __restrict__ outh,
                      unsigned short* __restrict__ outl)
{
    constexpr int TQ = 128, TK = 64, LD = 72;   // LD: +8 pad, rows 144B (16B-aligned)
    __shared__ unsigned short Ksh[TK][LD], Ksl[TK][LD];   // [key][d]
    __shared__ unsigned short Vth[D_][LD], Vtl[D_][LD];   // [d][key]
    __shared__ unsigned short Ps[TQ][LD];                 // [q][key] bf16

    const int tid  = threadIdx.x;
    const int lane = tid & 63;
    const int wave = tid >> 6;
    const int ln = lane & 15, qd = lane >> 4;
    const int qblk = blockIdx.x, h = blockIdx.y, b = blockIdx.z;
    const int wq0 = wave * 32;

    // ---- load Q fragments once (A-operand layout, split) ----
    short8 qh[2][2], ql[2][2];
    #pragma unroll
    for (int mt = 0; mt < 2; ++mt)
        #pragma unroll
        for (int ks = 0; ks < 2; ++ks) {
            size_t base = ((size_t)(b * S_ + qblk * TQ + wq0 + mt * 16 + ln)) * (3 * E_)
                        + h * 64 + ks * 32 + qd * 8;
            qh[mt][ks] = *(const short8*)(qkvh + base);
            ql[mt][ks] = *(const short8*)(qkvl + base);
        }

    f32x4 o[2][4] = {};
    float m_run[2][4], l_run[2][4];
    #pragma unroll
    for (int mt = 0; mt < 2; ++mt)
        #pragma unroll
        for (int r = 0; r < 4; ++r) { m_run[mt][r] = -INFINITY; l_run[mt][r] = 0.f; }

    // staging coords
    const int krow = tid >> 2, kcol = (tid & 3) * 16;          // K: [key][d]
    const int vkey = (tid & 31) * 2, vdc = (tid >> 5) * 8;     // V: 2 keys x 8 d

    for (int kb = 0; kb < S_; kb += TK) {
        __syncthreads();
        // ---- stage K (natural layout) ----
        {
            size_t gb = ((size_t)(b * S_ + kb + krow)) * (3 * E_) + E_ + h * 64 + kcol;
            *(ushort8_t*)&Ksh[krow][kcol]     = *(const ushort8_t*)(qkvh + gb);
            *(ushort8_t*)&Ksh[krow][kcol + 8] = *(const ushort8_t*)(qkvh + gb + 8);
            *(ushort8_t*)&Ksl[krow][kcol]     = *(const ushort8_t*)(qkvl + gb);
            *(ushort8_t*)&Ksl[krow][kcol + 8] = *(const ushort8_t*)(qkvl + gb + 8);
        }
        // ---- stage V transposed (pack key-pairs into u32 writes) ----
        {
            size_t vb0 = ((size_t)(b * S_ + kb + vkey)) * (3 * E_) + 2 * E_ + h * 64 + vdc;
            size_t vb1 = vb0 + 3 * E_;
            ushort8_t v0h = *(const ushort8_t*)(qkvh + vb0);
            ushort8_t v1h = *(const ushort8_t*)(qkvh + vb1);
            ushort8_t v0l = *(const ushort8_t*)(qkvl + vb0);
            ushort8_t v1l = *(const ushort8_t*)(qkvl + vb1);
            #pragma unroll
            for (int j = 0; j < 8; ++j) {
                *(unsigned*)&Vth[vdc + j][vkey] =
                    (unsigned)v0h[j] | ((unsigned)v1h[j] << 16);
                *(unsigned*)&Vtl[vdc + j][vkey] =
                    (unsigned)v0l[j] | ((unsigned)v1l[j] << 16);
            }
        }
        __syncthreads();

        // ---- S = Q K^T (split x split, 3 mfma) ----
        f32x4 s[2][4] = {};
        #pragma unroll
        for (int ks = 0; ks < 2; ++ks) {
            short8 kh[4], kl[4];
            #pragma unroll
            for (int nt = 0; nt < 4; ++nt) {
                kh[nt] = *(const short8*)&Ksh[nt * 16 + ln][ks * 32 + qd * 8];
                kl[nt] = *(const short8*)&Ksl[nt * 16 + ln][ks * 32 + qd * 8];
            }
            #pragma unroll
            for (int mt = 0; mt < 2; ++mt)
                #pragma unroll
                for (int nt = 0; nt < 4; ++nt) {
                    s[mt][nt] = __builtin_amdgcn_mfma_f32_16x16x32_bf16(
                        qh[mt][ks], kh[nt], s[mt][nt], 0, 0, 0);
                    s[mt][nt] = __builtin_amdgcn_mfma_f32_16x16x32_bf16(
                        qh[mt][ks], kl[nt], s[mt][nt], 0, 0, 0);
                    s[mt][nt] = __builtin_amdgcn_mfma_f32_16x16x32_bf16(
                        ql[mt][ks], kh[nt], s[mt][nt], 0, 0, 0);
                }
        }

        // ---- online softmax (scale 1/sqrt(64) = 0.125 folded here) ----
        #pragma unroll
        for (int mt = 0; mt < 2; ++mt)
            #pragma unroll
            for (int r = 0; r < 4; ++r) {
                float s0 = s[mt][0][r] * 0.125f;
                float s1 = s[mt][1][r] * 0.125f;
                float s2 = s[mt][2][r] * 0.125f;
                float s3 = s[mt][3][r] * 0.125f;
                float mx = fmaxf(fmaxf(s0, s1), fmaxf(s2, s3));
                mx = fmaxf(mx, __shfl_xor(mx, 1));
                mx = fmaxf(mx, __shfl_xor(mx, 2));
                mx = fmaxf(mx, __shfl_xor(mx, 4));
                mx = fmaxf(mx, __shfl_xor(mx, 8));
                float mn = fmaxf(m_run[mt][r], mx);
                float alpha = __expf(m_run[mt][r] - mn);
                m_run[mt][r] = mn;
                s0 = __expf(s0 - mn); s1 = __expf(s1 - mn);
                s2 = __expf(s2 - mn); s3 = __expf(s3 - mn);
                s[mt][0][r] = s0; s[mt][1][r] = s1;
                s[mt][2][r] = s2; s[mt][3][r] = s3;
                float rs = (s0 + s1) + (s2 + s3);
                rs += __shfl_xor(rs, 1);
                rs += __shfl_xor(rs, 2);
                rs += __shfl_xor(rs, 4);
                rs += __shfl_xor(rs, 8);
                l_run[mt][r] = l_run[mt][r] * alpha + rs;
                #pragma unroll
                for (int nt = 0; nt < 4; ++nt) o[mt][nt][r] *= alpha;
            }

        // ---- P -> LDS (C-layout scatter, bf16) ----
        #pragma unroll
        for (int mt = 0; mt < 2; ++mt)
            #pragma unroll
            for (int nt = 0; nt < 4; ++nt)
                #pragma unroll
                for (int r = 0; r < 4; ++r)
                    Ps[wq0 + mt * 16 + qd * 4 + r][nt * 16 + ln] = f2b(s[mt][nt][r]);
        __syncthreads();

        // ---- O += P V (bf16 P x split V, 2 mfma) ----
        #pragma unroll
        for (int ks = 0; ks < 2; ++ks) {
            short8 ph[2], vh[4], vl[4];
            #pragma unroll
            for (int mt = 0; mt < 2; ++mt)
                ph[mt] = *(const short8*)&Ps[wq0 + mt * 16 + ln][ks * 32 + qd * 8];
            #pragma unroll
            for (int nt = 0; nt < 4; ++nt) {
                vh[nt] = *(const short8*)&Vth[nt * 16 + ln][ks * 32 + qd * 8];
                vl[nt] = *(const short8*)&Vtl[nt * 16 + ln][ks * 32 + qd * 8];
            }
            #pragma unroll
            for (int mt = 0; mt < 2; ++mt)
                #pragma unroll
                for (int nt = 0; nt < 4; ++nt) {
                    o[mt][nt] = __builtin_amdgcn_mfma_f32_16x16x32_bf16(
                        ph[mt], vh[nt], o[mt][nt], 0, 0, 0);
                    o[mt][nt] = __builtin_amdgcn_mfma_f32_16x16x32_bf16(
                        ph[mt], vl[nt], o[mt][nt], 0, 0, 0);
                }
        }
    }

    // ---- epilogue: normalize, split-store ----
    #pragma unroll
    for (int mt = 0; mt < 2; ++mt) {
        float inv[4];
        #pragma unroll
        for (int r = 0; r < 4; ++r) inv[r] = 1.0f / l_run[mt][r];
        #pragma unroll
        for (int nt = 0; nt < 4; ++nt) {
            const int dd = h * 64 + nt * 16 + ln;
            #pragma unroll
            for (int r = 0; r < 4; ++r) {
                const int q = qblk * TQ + wq0 + mt * 16 + qd * 4 + r;
                size_t idx = ((size_t)(b * S_ + q)) * E_ + dd;
                unsigned short hh, ll;
                splitf(o[mt][nt][r] * inv[r], hh, ll);
                outh[idx] = hh;
                outl[idx] = ll;
            }
        }
    }
}

// ---------------------------------------------------------------------------
extern "C" void kernel_launch(void* const* d_in, const int* in_sizes, int n_in,
                              void* d_out, int out_size, void* d_ws, size_t ws_size,
                              hipStream_t stream)
{
    const float* x     = (const float*)d_in[0];   // [B,S,E]
    const float* w_in  = (const float*)d_in[1];   // [E,3E]
    const float* b_in  = (const float*)d_in[2];   // [3E]
    const float* w_out = (const float*)d_in[3];   // [E,E]
    const float* b_out = (const float*)d_in[4];   // [E]
    float* outp = (float*)d_out;

    char* ws = (char*)d_ws;
    unsigned short* qkvh = (unsigned short*)ws;                               // 50.33 MB
    unsigned short* qkvl = qkvh + (size_t)M_ * 3 * E_;                        // 50.33 MB
    unsigned short* attnh = qkvl + (size_t)M_ * 3 * E_;                       // 16.78 MB
    unsigned short* attnl = attnh + (size_t)M_ * E_;                          // 16.78 MB
    unsigned short* wInTh = attnh;            // transient, in not-yet-written attn region
    unsigned short* wInTl = wInTh + (size_t)3 * E_ * E_;
    unsigned short* wOutTh = qkvh;            // transient, in dead-after-attn qkv region
    unsigned short* wOutTl = wOutTh + (size_t)E_ * E_;

    // 1) wInT = transpose+split(w_in)
    transpose_split_kernel<<<dim3(3 * E_ / 32, E_ / 32), 256, 0, stream>>>(
        w_in, wInTh, wInTl, E_, 3 * E_);

    // 2) qkv = x @ w_in + b_in  (split output)
    gemm_mfma_kernel<false, true><<<dim3(M_ / 128, (3 * E_) / 128), 256, 0, stream>>>(
        x, nullptr, nullptr, wInTh, wInTl, b_in, nullptr, qkvh, qkvl,
        M_, 3 * E_, E_);

    // 3) MFMA flash attention, writes split attn
    attn_mfma_kernel<<<dim3(S_ / 128, H_, B_), 256, 0, stream>>>(
        qkvh, qkvl, attnh, attnl);

    // 4) wOutT = transpose+split(w_out)
    transpose_split_kernel<<<dim3(E_ / 32, E_ / 32), 256, 0, stream>>>(
        w_out, wOutTh, wOutTl, E_, E_);

    // 5) out = attn @ w_out + b_out
    gemm_mfma_kernel<true, false><<<dim3(M_ / 128, E_ / 128), 256, 0, stream>>>(
        nullptr, attnh, attnl, wOutTh, wOutTl, b_out, outp, nullptr, nullptr,
        M_, E_, E_);
}

// Round 4
// 573.916 us; speedup vs baseline: 3.2613x; 1.3693x over previous
//
#include <hip/hip_runtime.h>
#include <math.h>

#define B_ 4
#define S_ 2048
#define E_ 1024
#define H_ 16
#define D_ 64
#define M_ (B_ * S_)   // 8192

using f32x4  = __attribute__((ext_vector_type(4))) float;
using short8 = __attribute__((ext_vector_type(8))) short;
using ushort8_t = __attribute__((ext_vector_type(8))) unsigned short;

// split f into hi (bf16 truncation) + lo (bf16 RNE of residual); hi+lo ~= f to 2^-17
__device__ inline void splitf(float f, unsigned short& h, unsigned short& l) {
    unsigned u = __float_as_uint(f);
    h = (unsigned short)(u >> 16);
    float hf = __uint_as_float(u & 0xffff0000u);
    float lf = f - hf;                      // exact
    unsigned v = __float_as_uint(lf);
    l = (unsigned short)((v + 0x7fffu + ((v >> 16) & 1u)) >> 16);   // RNE
}
__device__ inline unsigned short f2b(float f) {   // fp32 -> bf16 RNE
    unsigned v = __float_as_uint(f);
    return (unsigned short)((v + 0x7fffu + ((v >> 16) & 1u)) >> 16);
}

// ---------------------------------------------------------------------------
// transpose + split: W[R][C] fp32  ->  Th/Tl[C][R] bf16
// ---------------------------------------------------------------------------
__global__ __launch_bounds__(256)
void transpose_split_kernel(const float* __restrict__ W,
                            unsigned short* __restrict__ Th,
                            unsigned short* __restrict__ Tl, int R, int C)
{
    __shared__ float t[32][33];
    const int tx = threadIdx.x & 31, ty = threadIdx.x >> 5;   // ty 0..7
    const int c0 = blockIdx.x * 32, r0 = blockIdx.y * 32;
    #pragma unroll
    for (int i = 0; i < 4; ++i)
        t[ty + 8 * i][tx] = W[(size_t)(r0 + ty + 8 * i) * C + c0 + tx];
    __syncthreads();
    #pragma unroll
    for (int i = 0; i < 4; ++i) {
        float v = t[tx][ty + 8 * i];
        unsigned short h, l;
        splitf(v, h, l);
        size_t idx = (size_t)(c0 + ty + 8 * i) * R + r0 + tx;
        Th[idx] = h;
        Tl[idx] = l;
    }
}

// ---------------------------------------------------------------------------
// Split-bf16 MFMA GEMM (unchanged from R3)
// ---------------------------------------------------------------------------
template<bool A_SPLIT_IN, bool OUT_SPLIT>
__global__ __launch_bounds__(256)
void gemm_mfma_kernel(const float* __restrict__ Af,
                      const unsigned short* __restrict__ Ah,
                      const unsigned short* __restrict__ Al,
                      const unsigned short* __restrict__ Bth,
                      const unsigned short* __restrict__ Btl,
                      const float* __restrict__ bias,
                      float* __restrict__ Cf,
                      unsigned short* __restrict__ Ch,
                      unsigned short* __restrict__ Cl,
                      int M, int N, int K)
{
    constexpr int LDK = 40;
    __shared__ unsigned short AsH[128][LDK];
    __shared__ unsigned short AsL[128][LDK];
    __shared__ unsigned short BsH[128][LDK];
    __shared__ unsigned short BsL[128][LDK];

    const int tid  = threadIdx.x;
    const int lane = tid & 63;
    const int wave = tid >> 6;
    const int wm = (wave >> 1) * 64, wn = (wave & 1) * 64;
    const int ln = lane & 15, qd = lane >> 4;
    const int m0 = blockIdx.x * 128, n0 = blockIdx.y * 128;

    f32x4 acc[4][4] = {};

    for (int k0 = 0; k0 < K; k0 += 32) {
        if (!A_SPLIT_IN) {
            #pragma unroll
            for (int i = 0; i < 4; ++i) {
                int g = tid + 256 * i;
                int row = g >> 3, kc = (g & 7) * 4;
                float4 v = *(const float4*)(Af + (size_t)(m0 + row) * K + k0 + kc);
                ushort4 hv, lv;
                splitf(v.x, hv.x, lv.x);
                splitf(v.y, hv.y, lv.y);
                splitf(v.z, hv.z, lv.z);
                splitf(v.w, hv.w, lv.w);
                *(ushort4*)&AsH[row][kc] = hv;
                *(ushort4*)&AsL[row][kc] = lv;
            }
        } else {
            #pragma unroll
            for (int i = 0; i < 2; ++i) {
                int g = tid + 256 * i;
                int row = g >> 2, kc = (g & 3) * 8;
                *(ushort8_t*)&AsH[row][kc] =
                    *(const ushort8_t*)(Ah + (size_t)(m0 + row) * K + k0 + kc);
                *(ushort8_t*)&AsL[row][kc] =
                    *(const ushort8_t*)(Al + (size_t)(m0 + row) * K + k0 + kc);
            }
        }
        #pragma unroll
        for (int i = 0; i < 2; ++i) {
            int g = tid + 256 * i;
            int row = g >> 2, kc = (g & 3) * 8;
            *(ushort8_t*)&BsH[row][kc] =
                *(const ushort8_t*)(Bth + (size_t)(n0 + row) * K + k0 + kc);
            *(ushort8_t*)&BsL[row][kc] =
                *(const ushort8_t*)(Btl + (size_t)(n0 + row) * K + k0 + kc);
        }
        __syncthreads();

        short8 ah[4], al[4], bh[4], bl[4];
        #pragma unroll
        for (int mt = 0; mt < 4; ++mt) {
            ah[mt] = *(const short8*)&AsH[wm + mt * 16 + ln][qd * 8];
            al[mt] = *(const short8*)&AsL[wm + mt * 16 + ln][qd * 8];
        }
        #pragma unroll
        for (int nt = 0; nt < 4; ++nt) {
            bh[nt] = *(const short8*)&BsH[wn + nt * 16 + ln][qd * 8];
            bl[nt] = *(const short8*)&BsL[wn + nt * 16 + ln][qd * 8];
        }
        #pragma unroll
        for (int mt = 0; mt < 4; ++mt)
            #pragma unroll
            for (int nt = 0; nt < 4; ++nt) {
                acc[mt][nt] = __builtin_amdgcn_mfma_f32_16x16x32_bf16(
                    ah[mt], bh[nt], acc[mt][nt], 0, 0, 0);
                acc[mt][nt] = __builtin_amdgcn_mfma_f32_16x16x32_bf16(
                    ah[mt], bl[nt], acc[mt][nt], 0, 0, 0);
                acc[mt][nt] = __builtin_amdgcn_mfma_f32_16x16x32_bf16(
                    al[mt], bh[nt], acc[mt][nt], 0, 0, 0);
            }
        __syncthreads();
    }

    #pragma unroll
    for (int nt = 0; nt < 4; ++nt) {
        const int col = n0 + wn + nt * 16 + ln;
        const float bv = bias[col];
        #pragma unroll
        for (int mt = 0; mt < 4; ++mt) {
            #pragma unroll
            for (int r = 0; r < 4; ++r) {
                const int row = m0 + wm + mt * 16 + qd * 4 + r;
                float f = acc[mt][nt][r] + bv;
                size_t idx = (size_t)row * N + col;
                if (OUT_SPLIT) {
                    unsigned short h, l;
                    splitf(f, h, l);
                    Ch[idx] = h;
                    Cl[idx] = l;
                } else {
                    Cf[idx] = f;
                }
            }
        }
    }
}

// ---------------------------------------------------------------------------
// MFMA flash attention, transposed form. Block = (b,h,128-q); 4 waves x 32 q.
//   S^T = K Q^T  (A = K split, B = Q split; C lanes = q, rows = key)
//   softmax: fixed m=0, per-lane partial row-sums, reduction deferred to end
//   P^T scatter: 4 key-contiguous bf16 -> ds_write_b64 (wave-private, no barrier)
//   O^T = V^T P^T (A = V^T bf16, B = P^T; C lanes = q, rows = d)
// Register prefetch of next K/V tile overlaps compute; 2 barriers/iter.
// ---------------------------------------------------------------------------
__global__ __launch_bounds__(256, 3)
void attn_mfma_kernel(const unsigned short* __restrict__ qkvh,
                      const unsigned short* __restrict__ qkvl,
                      unsigned short* __restrict__ outh,
                      unsigned short* __restrict__ outl)
{
    constexpr int TQ = 128, TK = 64, LD = 72;   // LD pad: rows 144B (16B-aligned)
    __shared__ unsigned short Ksh[TK][LD], Ksl[TK][LD];   // [key][d]
    __shared__ unsigned short Vth[D_][LD];                // [d][key] (bf16 hi only)
    __shared__ unsigned short Ps[TQ][LD];                 // [q][key] bf16

    const int tid  = threadIdx.x;
    const int lane = tid & 63;
    const int wave = tid >> 6;
    const int ln = lane & 15, qd = lane >> 4;
    const int qblk = blockIdx.x, h = blockIdx.y, b = blockIdx.z;
    const int wq0 = wave * 32;

    // ---- Q fragments (B-operand: lane = q, k = d), split ----
    short8 qh[2][2], ql[2][2];
    #pragma unroll
    for (int qt = 0; qt < 2; ++qt)
        #pragma unroll
        for (int ks = 0; ks < 2; ++ks) {
            size_t base = ((size_t)(b * S_ + qblk * TQ + wq0 + qt * 16 + ln)) * (3 * E_)
                        + h * 64 + ks * 32 + qd * 8;
            qh[qt][ks] = *(const short8*)(qkvh + base);
            ql[qt][ks] = *(const short8*)(qkvl + base);
        }

    f32x4 o[4][2] = {};          // [dt][qt]
    float lsum[2] = {0.f, 0.f};  // per-lane partial row sums (fixed m=0)

    // staging coords
    const int krow = tid >> 2, kcol = (tid & 3) * 16;       // K: [key][d]
    const int vkey = (tid & 31) * 2, vdc = (tid >> 5) * 8;  // V: 2 keys x 8 d

    // ---- prologue: prefetch tile 0 into registers ----
    ushort8_t pk0, pk1, pk2, pk3, pv0, pv1;
    {
        size_t gb = ((size_t)(b * S_ + krow)) * (3 * E_) + E_ + h * 64 + kcol;
        pk0 = *(const ushort8_t*)(qkvh + gb);
        pk1 = *(const ushort8_t*)(qkvh + gb + 8);
        pk2 = *(const ushort8_t*)(qkvl + gb);
        pk3 = *(const ushort8_t*)(qkvl + gb + 8);
        size_t vb0 = ((size_t)(b * S_ + vkey)) * (3 * E_) + 2 * E_ + h * 64 + vdc;
        pv0 = *(const ushort8_t*)(qkvh + vb0);
        pv1 = *(const ushort8_t*)(qkvh + vb0 + 3 * E_);
    }

    for (int kb = 0; kb < S_; kb += TK) {
        // ---- write staged regs -> LDS ----
        *(ushort8_t*)&Ksh[krow][kcol]     = pk0;
        *(ushort8_t*)&Ksh[krow][kcol + 8] = pk1;
        *(ushort8_t*)&Ksl[krow][kcol]     = pk2;
        *(ushort8_t*)&Ksl[krow][kcol + 8] = pk3;
        #pragma unroll
        for (int j = 0; j < 8; ++j)
            *(unsigned*)&Vth[vdc + j][vkey] =
                (unsigned)pv0[j] | ((unsigned)pv1[j] << 16);
        __syncthreads();

        // ---- prefetch next tile (overlaps all compute below) ----
        if (kb + TK < S_) {
            size_t gb = ((size_t)(b * S_ + kb + TK + krow)) * (3 * E_) + E_ + h * 64 + kcol;
            pk0 = *(const ushort8_t*)(qkvh + gb);
            pk1 = *(const ushort8_t*)(qkvh + gb + 8);
            pk2 = *(const ushort8_t*)(qkvl + gb);
            pk3 = *(const ushort8_t*)(qkvl + gb + 8);
            size_t vb0 = ((size_t)(b * S_ + kb + TK + vkey)) * (3 * E_) + 2 * E_ + h * 64 + vdc;
            pv0 = *(const ushort8_t*)(qkvh + vb0);
            pv1 = *(const ushort8_t*)(qkvh + vb0 + 3 * E_);
        }

        // ---- S^T = K Q^T (split x split, 3 mfma) ----
        f32x4 st[4][2] = {};   // [kt][qt]: lane=q, rows=key kt*16+qd*4+r
        #pragma unroll
        for (int ks = 0; ks < 2; ++ks) {
            short8 kh[4], kl[4];
            #pragma unroll
            for (int kt = 0; kt < 4; ++kt) {
                kh[kt] = *(const short8*)&Ksh[kt * 16 + ln][ks * 32 + qd * 8];
                kl[kt] = *(const short8*)&Ksl[kt * 16 + ln][ks * 32 + qd * 8];
            }
            #pragma unroll
            for (int kt = 0; kt < 4; ++kt)
                #pragma unroll
                for (int qt = 0; qt < 2; ++qt) {
                    st[kt][qt] = __builtin_amdgcn_mfma_f32_16x16x32_bf16(
                        kh[kt], qh[qt][ks], st[kt][qt], 0, 0, 0);
                    st[kt][qt] = __builtin_amdgcn_mfma_f32_16x16x32_bf16(
                        kh[kt], ql[qt][ks], st[kt][qt], 0, 0, 0);
                    st[kt][qt] = __builtin_amdgcn_mfma_f32_16x16x32_bf16(
                        kl[kt], qh[qt][ks], st[kt][qt], 0, 0, 0);
                }
        }

        // ---- softmax (m=0): p = exp2(s * 0.125*log2e); pack 4 keys -> b64 ----
        #pragma unroll
        for (int qt = 0; qt < 2; ++qt)
            #pragma unroll
            for (int kt = 0; kt < 4; ++kt) {
                ushort4 pk4;
                float p0 = exp2f(st[kt][qt][0] * 0.18033688f);
                float p1 = exp2f(st[kt][qt][1] * 0.18033688f);
                float p2 = exp2f(st[kt][qt][2] * 0.18033688f);
                float p3 = exp2f(st[kt][qt][3] * 0.18033688f);
                lsum[qt] += (p0 + p1) + (p2 + p3);
                pk4.x = f2b(p0); pk4.y = f2b(p1);
                pk4.z = f2b(p2); pk4.w = f2b(p3);
                *(ushort4*)&Ps[wq0 + qt * 16 + ln][kt * 16 + qd * 4] = pk4;
            }
        // Ps rows are wave-private: no barrier needed before PV reads.

        // ---- O^T += V^T P^T ----
        #pragma unroll
        for (int ks = 0; ks < 2; ++ks) {
            short8 vA[4], pB[2];
            #pragma unroll
            for (int dt = 0; dt < 4; ++dt)
                vA[dt] = *(const short8*)&Vth[dt * 16 + ln][ks * 32 + qd * 8];
            #pragma unroll
            for (int qt = 0; qt < 2; ++qt)
                pB[qt] = *(const short8*)&Ps[wq0 + qt * 16 + ln][ks * 32 + qd * 8];
            #pragma unroll
            for (int dt = 0; dt < 4; ++dt)
                #pragma unroll
                for (int qt = 0; qt < 2; ++qt)
                    o[dt][qt] = __builtin_amdgcn_mfma_f32_16x16x32_bf16(
                        vA[dt], pB[qt], o[dt][qt], 0, 0, 0);
        }
        __syncthreads();   // protect Ks/Vth before next iteration's writes
    }

    // ---- deferred l reduction (across qd groups) + epilogue ----
    float inv[2];
    #pragma unroll
    for (int qt = 0; qt < 2; ++qt) {
        float l = lsum[qt];
        l += __shfl_xor(l, 16);
        l += __shfl_xor(l, 32);
        inv[qt] = 1.0f / l;
    }
    #pragma unroll
    for (int qt = 0; qt < 2; ++qt) {
        const int q = qblk * TQ + wq0 + qt * 16 + ln;
        #pragma unroll
        for (int dt = 0; dt < 4; ++dt) {
            size_t base = ((size_t)(b * S_ + q)) * E_ + h * 64 + dt * 16 + qd * 4;
            ushort4 hh, ll;
            #pragma unroll
            for (int r = 0; r < 4; ++r) {
                unsigned short h2, l2;
                splitf(o[dt][qt][r] * inv[qt], h2, l2);
                ((unsigned short*)&hh)[r] = h2;
                ((unsigned short*)&ll)[r] = l2;
            }
            *(ushort4*)(outh + base) = hh;
            *(ushort4*)(outl + base) = ll;
        }
    }
}

// ---------------------------------------------------------------------------
extern "C" void kernel_launch(void* const* d_in, const int* in_sizes, int n_in,
                              void* d_out, int out_size, void* d_ws, size_t ws_size,
                              hipStream_t stream)
{
    const float* x     = (const float*)d_in[0];   // [B,S,E]
    const float* w_in  = (const float*)d_in[1];   // [E,3E]
    const float* b_in  = (const float*)d_in[2];   // [3E]
    const float* w_out = (const float*)d_in[3];   // [E,E]
    const float* b_out = (const float*)d_in[4];   // [E]
    float* outp = (float*)d_out;

    char* ws = (char*)d_ws;
    unsigned short* qkvh = (unsigned short*)ws;                               // 50.33 MB
    unsigned short* qkvl = qkvh + (size_t)M_ * 3 * E_;                        // 50.33 MB
    unsigned short* attnh = qkvl + (size_t)M_ * 3 * E_;                       // 16.78 MB
    unsigned short* attnl = attnh + (size_t)M_ * E_;                          // 16.78 MB
    unsigned short* wInTh = attnh;            // transient, in not-yet-written attn region
    unsigned short* wInTl = wInTh + (size_t)3 * E_ * E_;
    unsigned short* wOutTh = qkvh;            // transient, in dead-after-attn qkv region
    unsigned short* wOutTl = wOutTh + (size_t)E_ * E_;

    // 1) wInT = transpose+split(w_in)
    transpose_split_kernel<<<dim3(3 * E_ / 32, E_ / 32), 256, 0, stream>>>(
        w_in, wInTh, wInTl, E_, 3 * E_);

    // 2) qkv = x @ w_in + b_in  (split output)
    gemm_mfma_kernel<false, true><<<dim3(M_ / 128, (3 * E_) / 128), 256, 0, stream>>>(
        x, nullptr, nullptr, wInTh, wInTl, b_in, nullptr, qkvh, qkvl,
        M_, 3 * E_, E_);

    // 3) MFMA flash attention (transposed form), writes split attn
    attn_mfma_kernel<<<dim3(S_ / 128, H_, B_), 256, 0, stream>>>(
        qkvh, qkvl, attnh, attnl);

    // 4) wOutT = transpose+split(w_out)
    transpose_split_kernel<<<dim3(E_ / 32, E_ / 32), 256, 0, stream>>>(
        w_out, wOutTh, wOutTl, E_, E_);

    // 5) out = attn @ w_out + b_out
    gemm_mfma_kernel<true, false><<<dim3(M_ / 128, E_ / 128), 256, 0, stream>>>(
        nullptr, attnh, attnl, wOutTh, wOutTl, b_out, outp, nullptr, nullptr,
        M_, E_, E_);
}

// Round 5
// 497.760 us; speedup vs baseline: 3.7603x; 1.1530x over previous
//
#include <hip/hip_runtime.h>
#include <math.h>

#define B_ 4
#define S_ 2048
#define E_ 1024
#define H_ 16
#define D_ 64
#define M_ (B_ * S_)   // 8192

using f32x4  = __attribute__((ext_vector_type(4))) float;
using short8 = __attribute__((ext_vector_type(8))) short;
using ushort8_t = __attribute__((ext_vector_type(8))) unsigned short;

// split f into hi (bf16 truncation) + lo (bf16 RNE of residual); hi+lo ~= f to 2^-17
__device__ inline void splitf(float f, unsigned short& h, unsigned short& l) {
    unsigned u = __float_as_uint(f);
    h = (unsigned short)(u >> 16);
    float hf = __uint_as_float(u & 0xffff0000u);
    float lf = f - hf;                      // exact
    unsigned v = __float_as_uint(lf);
    l = (unsigned short)((v + 0x7fffu + ((v >> 16) & 1u)) >> 16);   // RNE
}
__device__ inline unsigned short f2b(float f) {   // fp32 -> bf16 RNE
    unsigned v = __float_as_uint(f);
    return (unsigned short)((v + 0x7fffu + ((v >> 16) & 1u)) >> 16);
}

// ---------------------------------------------------------------------------
// transpose + split: W[R][C] fp32  ->  Th/Tl[C][R] bf16
// ---------------------------------------------------------------------------
__global__ __launch_bounds__(256)
void transpose_split_kernel(const float* __restrict__ W,
                            unsigned short* __restrict__ Th,
                            unsigned short* __restrict__ Tl, int R, int C)
{
    __shared__ float t[32][33];
    const int tx = threadIdx.x & 31, ty = threadIdx.x >> 5;   // ty 0..7
    const int c0 = blockIdx.x * 32, r0 = blockIdx.y * 32;
    #pragma unroll
    for (int i = 0; i < 4; ++i)
        t[ty + 8 * i][tx] = W[(size_t)(r0 + ty + 8 * i) * C + c0 + tx];
    __syncthreads();
    #pragma unroll
    for (int i = 0; i < 4; ++i) {
        float v = t[tx][ty + 8 * i];
        unsigned short h, l;
        splitf(v, h, l);
        size_t idx = (size_t)(c0 + ty + 8 * i) * R + r0 + tx;
        Th[idx] = h;
        Tl[idx] = l;
    }
}

// ---------------------------------------------------------------------------
// Split-bf16 MFMA GEMM (unchanged)
// ---------------------------------------------------------------------------
template<bool A_SPLIT_IN, bool OUT_SPLIT>
__global__ __launch_bounds__(256)
void gemm_mfma_kernel(const float* __restrict__ Af,
                      const unsigned short* __restrict__ Ah,
                      const unsigned short* __restrict__ Al,
                      const unsigned short* __restrict__ Bth,
                      const unsigned short* __restrict__ Btl,
                      const float* __restrict__ bias,
                      float* __restrict__ Cf,
                      unsigned short* __restrict__ Ch,
                      unsigned short* __restrict__ Cl,
                      int M, int N, int K)
{
    constexpr int LDK = 40;
    __shared__ unsigned short AsH[128][LDK];
    __shared__ unsigned short AsL[128][LDK];
    __shared__ unsigned short BsH[128][LDK];
    __shared__ unsigned short BsL[128][LDK];

    const int tid  = threadIdx.x;
    const int lane = tid & 63;
    const int wave = tid >> 6;
    const int wm = (wave >> 1) * 64, wn = (wave & 1) * 64;
    const int ln = lane & 15, qd = lane >> 4;
    const int m0 = blockIdx.x * 128, n0 = blockIdx.y * 128;

    f32x4 acc[4][4] = {};

    for (int k0 = 0; k0 < K; k0 += 32) {
        if (!A_SPLIT_IN) {
            #pragma unroll
            for (int i = 0; i < 4; ++i) {
                int g = tid + 256 * i;
                int row = g >> 3, kc = (g & 7) * 4;
                float4 v = *(const float4*)(Af + (size_t)(m0 + row) * K + k0 + kc);
                ushort4 hv, lv;
                splitf(v.x, hv.x, lv.x);
                splitf(v.y, hv.y, lv.y);
                splitf(v.z, hv.z, lv.z);
                splitf(v.w, hv.w, lv.w);
                *(ushort4*)&AsH[row][kc] = hv;
                *(ushort4*)&AsL[row][kc] = lv;
            }
        } else {
            #pragma unroll
            for (int i = 0; i < 2; ++i) {
                int g = tid + 256 * i;
                int row = g >> 2, kc = (g & 3) * 8;
                *(ushort8_t*)&AsH[row][kc] =
                    *(const ushort8_t*)(Ah + (size_t)(m0 + row) * K + k0 + kc);
                *(ushort8_t*)&AsL[row][kc] =
                    *(const ushort8_t*)(Al + (size_t)(m0 + row) * K + k0 + kc);
            }
        }
        #pragma unroll
        for (int i = 0; i < 2; ++i) {
            int g = tid + 256 * i;
            int row = g >> 2, kc = (g & 3) * 8;
            *(ushort8_t*)&BsH[row][kc] =
                *(const ushort8_t*)(Bth + (size_t)(n0 + row) * K + k0 + kc);
            *(ushort8_t*)&BsL[row][kc] =
                *(const ushort8_t*)(Btl + (size_t)(n0 + row) * K + k0 + kc);
        }
        __syncthreads();

        short8 ah[4], al[4], bh[4], bl[4];
        #pragma unroll
        for (int mt = 0; mt < 4; ++mt) {
            ah[mt] = *(const short8*)&AsH[wm + mt * 16 + ln][qd * 8];
            al[mt] = *(const short8*)&AsL[wm + mt * 16 + ln][qd * 8];
        }
        #pragma unroll
        for (int nt = 0; nt < 4; ++nt) {
            bh[nt] = *(const short8*)&BsH[wn + nt * 16 + ln][qd * 8];
            bl[nt] = *(const short8*)&BsL[wn + nt * 16 + ln][qd * 8];
        }
        #pragma unroll
        for (int mt = 0; mt < 4; ++mt)
            #pragma unroll
            for (int nt = 0; nt < 4; ++nt) {
                acc[mt][nt] = __builtin_amdgcn_mfma_f32_16x16x32_bf16(
                    ah[mt], bh[nt], acc[mt][nt], 0, 0, 0);
                acc[mt][nt] = __builtin_amdgcn_mfma_f32_16x16x32_bf16(
                    ah[mt], bl[nt], acc[mt][nt], 0, 0, 0);
                acc[mt][nt] = __builtin_amdgcn_mfma_f32_16x16x32_bf16(
                    al[mt], bh[nt], acc[mt][nt], 0, 0, 0);
            }
        __syncthreads();
    }

    #pragma unroll
    for (int nt = 0; nt < 4; ++nt) {
        const int col = n0 + wn + nt * 16 + ln;
        const float bv = bias[col];
        #pragma unroll
        for (int mt = 0; mt < 4; ++mt) {
            #pragma unroll
            for (int r = 0; r < 4; ++r) {
                const int row = m0 + wm + mt * 16 + qd * 4 + r;
                float f = acc[mt][nt][r] + bv;
                size_t idx = (size_t)row * N + col;
                if (OUT_SPLIT) {
                    unsigned short h, l;
                    splitf(f, h, l);
                    Ch[idx] = h;
                    Cl[idx] = l;
                } else {
                    Cf[idx] = f;
                }
            }
        }
    }
}

// ---------------------------------------------------------------------------
// MFMA flash attention, transposed form (R4 structure).
// R5 changes ONLY:
//   (a) plain __launch_bounds__(256) — the (256,3) clamp forced VGPR=84 and
//       spilled ~50 regs/iter to scratch (WRITE_SIZE 32MiB -> 231MB in R4).
//   (b) 1-D swizzled grid: all 16 q-blocks of one (b,h) share id%8 -> same
//       XCD -> K/V stay L2-resident across q-blocks.
// ---------------------------------------------------------------------------
__global__ __launch_bounds__(256)
void attn_mfma_kernel(const unsigned short* __restrict__ qkvh,
                      const unsigned short* __restrict__ qkvl,
                      unsigned short* __restrict__ outh,
                      unsigned short* __restrict__ outl)
{
    constexpr int TQ = 128, TK = 64, LD = 72;   // LD pad: rows 144B (16B-aligned)
    __shared__ unsigned short Ksh[TK][LD], Ksl[TK][LD];   // [key][d]
    __shared__ unsigned short Vth[D_][LD];                // [d][key] (bf16 hi only)
    __shared__ unsigned short Ps[TQ][LD];                 // [q][key] bf16

    const int tid  = threadIdx.x;
    const int lane = tid & 63;
    const int wave = tid >> 6;
    const int ln = lane & 15, qd = lane >> 4;
    // XCD-aware decode: ids {g, g+64, g+128, ...} are the q-blocks of group g;
    // consecutive-id round-robin => all land on XCD g%8.
    const int id   = blockIdx.x;
    const int g    = id & 63;
    const int qblk = id >> 6;
    const int h    = g & 15;
    const int b    = g >> 4;
    const int wq0 = wave * 32;

    // ---- Q fragments (B-operand: lane = q, k = d), split ----
    short8 qh[2][2], ql[2][2];
    #pragma unroll
    for (int qt = 0; qt < 2; ++qt)
        #pragma unroll
        for (int ks = 0; ks < 2; ++ks) {
            size_t base = ((size_t)(b * S_ + qblk * TQ + wq0 + qt * 16 + ln)) * (3 * E_)
                        + h * 64 + ks * 32 + qd * 8;
            qh[qt][ks] = *(const short8*)(qkvh + base);
            ql[qt][ks] = *(const short8*)(qkvl + base);
        }

    f32x4 o[4][2] = {};          // [dt][qt]
    float lsum[2] = {0.f, 0.f};  // per-lane partial row sums (fixed m=0)

    // staging coords
    const int krow = tid >> 2, kcol = (tid & 3) * 16;       // K: [key][d]
    const int vkey = (tid & 31) * 2, vdc = (tid >> 5) * 8;  // V: 2 keys x 8 d

    // ---- prologue: prefetch tile 0 into registers ----
    ushort8_t pk0, pk1, pk2, pk3, pv0, pv1;
    {
        size_t gb = ((size_t)(b * S_ + krow)) * (3 * E_) + E_ + h * 64 + kcol;
        pk0 = *(const ushort8_t*)(qkvh + gb);
        pk1 = *(const ushort8_t*)(qkvh + gb + 8);
        pk2 = *(const ushort8_t*)(qkvl + gb);
        pk3 = *(const ushort8_t*)(qkvl + gb + 8);
        size_t vb0 = ((size_t)(b * S_ + vkey)) * (3 * E_) + 2 * E_ + h * 64 + vdc;
        pv0 = *(const ushort8_t*)(qkvh + vb0);
        pv1 = *(const ushort8_t*)(qkvh + vb0 + 3 * E_);
    }

    for (int kb = 0; kb < S_; kb += TK) {
        // ---- write staged regs -> LDS ----
        *(ushort8_t*)&Ksh[krow][kcol]     = pk0;
        *(ushort8_t*)&Ksh[krow][kcol + 8] = pk1;
        *(ushort8_t*)&Ksl[krow][kcol]     = pk2;
        *(ushort8_t*)&Ksl[krow][kcol + 8] = pk3;
        #pragma unroll
        for (int j = 0; j < 8; ++j)
            *(unsigned*)&Vth[vdc + j][vkey] =
                (unsigned)pv0[j] | ((unsigned)pv1[j] << 16);
        __syncthreads();

        // ---- prefetch next tile (overlaps all compute below) ----
        if (kb + TK < S_) {
            size_t gb = ((size_t)(b * S_ + kb + TK + krow)) * (3 * E_) + E_ + h * 64 + kcol;
            pk0 = *(const ushort8_t*)(qkvh + gb);
            pk1 = *(const ushort8_t*)(qkvh + gb + 8);
            pk2 = *(const ushort8_t*)(qkvl + gb);
            pk3 = *(const ushort8_t*)(qkvl + gb + 8);
            size_t vb0 = ((size_t)(b * S_ + kb + TK + vkey)) * (3 * E_) + 2 * E_ + h * 64 + vdc;
            pv0 = *(const ushort8_t*)(qkvh + vb0);
            pv1 = *(const ushort8_t*)(qkvh + vb0 + 3 * E_);
        }

        // ---- S^T = K Q^T (split x split, 3 mfma) ----
        f32x4 st[4][2] = {};   // [kt][qt]: lane=q, rows=key kt*16+qd*4+r
        #pragma unroll
        for (int ks = 0; ks < 2; ++ks) {
            short8 kh[4], kl[4];
            #pragma unroll
            for (int kt = 0; kt < 4; ++kt) {
                kh[kt] = *(const short8*)&Ksh[kt * 16 + ln][ks * 32 + qd * 8];
                kl[kt] = *(const short8*)&Ksl[kt * 16 + ln][ks * 32 + qd * 8];
            }
            #pragma unroll
            for (int kt = 0; kt < 4; ++kt)
                #pragma unroll
                for (int qt = 0; qt < 2; ++qt) {
                    st[kt][qt] = __builtin_amdgcn_mfma_f32_16x16x32_bf16(
                        kh[kt], qh[qt][ks], st[kt][qt], 0, 0, 0);
                    st[kt][qt] = __builtin_amdgcn_mfma_f32_16x16x32_bf16(
                        kh[kt], ql[qt][ks], st[kt][qt], 0, 0, 0);
                    st[kt][qt] = __builtin_amdgcn_mfma_f32_16x16x32_bf16(
                        kl[kt], qh[qt][ks], st[kt][qt], 0, 0, 0);
                }
        }

        // ---- softmax (m=0): p = exp2(s * 0.125*log2e); pack 4 keys -> b64 ----
        #pragma unroll
        for (int qt = 0; qt < 2; ++qt)
            #pragma unroll
            for (int kt = 0; kt < 4; ++kt) {
                ushort4 pk4;
                float p0 = exp2f(st[kt][qt][0] * 0.18033688f);
                float p1 = exp2f(st[kt][qt][1] * 0.18033688f);
                float p2 = exp2f(st[kt][qt][2] * 0.18033688f);
                float p3 = exp2f(st[kt][qt][3] * 0.18033688f);
                lsum[qt] += (p0 + p1) + (p2 + p3);
                pk4.x = f2b(p0); pk4.y = f2b(p1);
                pk4.z = f2b(p2); pk4.w = f2b(p3);
                *(ushort4*)&Ps[wq0 + qt * 16 + ln][kt * 16 + qd * 4] = pk4;
            }
        // Ps rows are wave-private: no barrier needed before PV reads.

        // ---- O^T += V^T P^T ----
        #pragma unroll
        for (int ks = 0; ks < 2; ++ks) {
            short8 vA[4], pB[2];
            #pragma unroll
            for (int dt = 0; dt < 4; ++dt)
                vA[dt] = *(const short8*)&Vth[dt * 16 + ln][ks * 32 + qd * 8];
            #pragma unroll
            for (int qt = 0; qt < 2; ++qt)
                pB[qt] = *(const short8*)&Ps[wq0 + qt * 16 + ln][ks * 32 + qd * 8];
            #pragma unroll
            for (int dt = 0; dt < 4; ++dt)
                #pragma unroll
                for (int qt = 0; qt < 2; ++qt)
                    o[dt][qt] = __builtin_amdgcn_mfma_f32_16x16x32_bf16(
                        vA[dt], pB[qt], o[dt][qt], 0, 0, 0);
        }
        __syncthreads();   // protect Ks/Vth before next iteration's writes
    }

    // ---- deferred l reduction (across qd groups) + epilogue ----
    float inv[2];
    #pragma unroll
    for (int qt = 0; qt < 2; ++qt) {
        float l = lsum[qt];
        l += __shfl_xor(l, 16);
        l += __shfl_xor(l, 32);
        inv[qt] = 1.0f / l;
    }
    #pragma unroll
    for (int qt = 0; qt < 2; ++qt) {
        const int q = qblk * TQ + wq0 + qt * 16 + ln;
        #pragma unroll
        for (int dt = 0; dt < 4; ++dt) {
            size_t base = ((size_t)(b * S_ + q)) * E_ + h * 64 + dt * 16 + qd * 4;
            ushort4 hh, ll;
            #pragma unroll
            for (int r = 0; r < 4; ++r) {
                unsigned short h2, l2;
                splitf(o[dt][qt][r] * inv[qt], h2, l2);
                ((unsigned short*)&hh)[r] = h2;
                ((unsigned short*)&ll)[r] = l2;
            }
            *(ushort4*)(outh + base) = hh;
            *(ushort4*)(outl + base) = ll;
        }
    }
}

// ---------------------------------------------------------------------------
extern "C" void kernel_launch(void* const* d_in, const int* in_sizes, int n_in,
                              void* d_out, int out_size, void* d_ws, size_t ws_size,
                              hipStream_t stream)
{
    const float* x     = (const float*)d_in[0];   // [B,S,E]
    const float* w_in  = (const float*)d_in[1];   // [E,3E]
    const float* b_in  = (const float*)d_in[2];   // [3E]
    const float* w_out = (const float*)d_in[3];   // [E,E]
    const float* b_out = (const float*)d_in[4];   // [E]
    float* outp = (float*)d_out;

    char* ws = (char*)d_ws;
    unsigned short* qkvh = (unsigned short*)ws;                               // 50.33 MB
    unsigned short* qkvl = qkvh + (size_t)M_ * 3 * E_;                        // 50.33 MB
    unsigned short* attnh = qkvl + (size_t)M_ * 3 * E_;                       // 16.78 MB
    unsigned short* attnl = attnh + (size_t)M_ * E_;                          // 16.78 MB
    unsigned short* wInTh = attnh;            // transient, in not-yet-written attn region
    unsigned short* wInTl = wInTh + (size_t)3 * E_ * E_;
    unsigned short* wOutTh = qkvh;            // transient, in dead-after-attn qkv region
    unsigned short* wOutTl = wOutTh + (size_t)E_ * E_;

    // 1) wInT = transpose+split(w_in)
    transpose_split_kernel<<<dim3(3 * E_ / 32, E_ / 32), 256, 0, stream>>>(
        w_in, wInTh, wInTl, E_, 3 * E_);

    // 2) qkv = x @ w_in + b_in  (split output)
    gemm_mfma_kernel<false, true><<<dim3(M_ / 128, (3 * E_) / 128), 256, 0, stream>>>(
        x, nullptr, nullptr, wInTh, wInTl, b_in, nullptr, qkvh, qkvl,
        M_, 3 * E_, E_);

    // 3) MFMA flash attention (transposed form), 1-D XCD-swizzled grid
    attn_mfma_kernel<<<dim3((S_ / 128) * H_ * B_), 256, 0, stream>>>(
        qkvh, qkvl, attnh, attnl);

    // 4) wOutT = transpose+split(w_out)
    transpose_split_kernel<<<dim3(E_ / 32, E_ / 32), 256, 0, stream>>>(
        w_out, wOutTh, wOutTl, E_, E_);

    // 5) out = attn @ w_out + b_out
    gemm_mfma_kernel<true, false><<<dim3(M_ / 128, E_ / 128), 256, 0, stream>>>(
        nullptr, attnh, attnl, wOutTh, wOutTl, b_out, outp, nullptr, nullptr,
        M_, E_, E_);
}